// Round 18
// baseline (38.615 us; speedup 1.0000x reference)
//
#include <hip/hip_runtime.h>
#include <hip/hip_bf16.h>

typedef __bf16 bf16x8 __attribute__((ext_vector_type(8)));
typedef _Float16 f16x8 __attribute__((ext_vector_type(8)));
typedef _Float16 f16x2 __attribute__((ext_vector_type(2)));
typedef float f32x4 __attribute__((ext_vector_type(4)));

#define B_DIM 16
#define L_DIM 1024
#define H_DIM 4
#define HC 128
#define TI 64
#define WPITCH 136   // bf16 elems; 272B rows, 16B-aligned
#define PROJ_BLOCKS 256

// ---------------------------------------------------------------------------
// Kernel 1 (heterogeneous prep, R16-proven): blocks 0..255 = projection
// (64 rows each), blocks 256..2303 = adjacency bit-pack (8 rows each).
// Proj blocks dispatch FIRST so CUs overlap the 64MB adj stream with proj's
// MFMA compute; kills one launch gap.
// ---------------------------------------------------------------------------
__global__ __launch_bounds__(256) void prep_kernel(
    const float* __restrict__ x, const float* __restrict__ W,
    const float* __restrict__ bias, const float* __restrict__ att_src,
    const float* __restrict__ att_dst, const int* __restrict__ adj,
    _Float16* __restrict__ xpT, _Float16* __restrict__ E1h,
    _Float16* __restrict__ E2h, float* __restrict__ Rr,
    unsigned* __restrict__ mask_g)
{
  __shared__ __align__(16) __bf16 Wlds[128 * WPITCH];   // 34.8 KB
  __shared__ __align__(16) __bf16 xh[64 * WPITCH];      // 17.4 KB
  __shared__ __align__(16) __bf16 xl[64 * WPITCH];      // 17.4 KB
  const int bid = blockIdx.x;
  const int t = threadIdx.x;
  const int wv = t >> 6, lane = t & 63;

  if (bid >= PROJ_BLOCKS) {
    // ---- mask role: rows (bid-256)*8 + wv*2 + {0,1} ----
    const int row0 = (bid - PROJ_BLOCKS) * 8 + wv * 2;
    const int* base = adj + (size_t)row0 * L_DIM;
    int4 av[8];
#pragma unroll
    for (int c = 0; c < 4; ++c) {
      av[c]     = *reinterpret_cast<const int4*>(base + c * 256 + lane * 4);
      av[c + 4] = *reinterpret_cast<const int4*>(base + 1024 + c * 256 + lane * 4);
    }
#pragma unroll
    for (int r = 0; r < 2; ++r) {
      const int row = row0 + r;
      const int i = row & (L_DIM - 1);
#pragma unroll
      for (int c = 0; c < 4; ++c) {
        const int4 u = av[r * 4 + c];
        unsigned b4 = (unsigned)u.x | ((unsigned)u.y << 1) |
                      ((unsigned)u.z << 2) | ((unsigned)u.w << 3);
        unsigned p;
        p = __shfl_xor(b4, 1);
        unsigned b8  = (lane & 1) ? (p | (b4 << 4))   : (b4 | (p << 4));
        p = __shfl_xor(b8, 2);
        unsigned b16 = (lane & 2) ? (p | (b8 << 8))   : (b8 | (p << 8));
        p = __shfl_xor(b16, 4);
        unsigned b32 = (lane & 4) ? (p | (b16 << 16)) : (b16 | (p << 16));
        const int widx = c * 8 + (lane >> 3);
        if ((i >> 5) == widx) b32 |= (1u << (i & 31));
        if ((lane & 7) == 0) mask_g[(size_t)row * 32 + widx] = b32;
      }
    }
    return;
  }

  // ---- proj role: rows bid*64 .. +63; wave w owns rows w*16..+15 ----
  const int r0 = bid * 64;
#pragma unroll
  for (int p = 0; p < 8; ++p) {
    const int idx = p * 2048 + t * 8;
    const int n = idx >> 7, k = idx & 127;
    const f32x4 a = *reinterpret_cast<const f32x4*>(W + idx);
    const f32x4 b = *reinterpret_cast<const f32x4*>(W + idx + 4);
    bf16x8 v;
#pragma unroll
    for (int e = 0; e < 4; ++e) { v[e] = (__bf16)a[e]; v[e + 4] = (__bf16)b[e]; }
    *reinterpret_cast<bf16x8*>(&Wlds[n * WPITCH + k]) = v;
  }
#pragma unroll
  for (int p = 0; p < 4; ++p) {
    const int idx = p * 2048 + t * 8;
    const int r = idx >> 7, k = idx & 127;
    const float* xp_ = x + (size_t)(r0 + r) * 128 + k;
    const f32x4 a = *reinterpret_cast<const f32x4*>(xp_);
    const f32x4 b = *reinterpret_cast<const f32x4*>(xp_ + 4);
    bf16x8 vh, vl;
#pragma unroll
    for (int e = 0; e < 4; ++e) {
      const float fa = a[e], fb = b[e];
      vh[e] = (__bf16)fa;          vh[e + 4] = (__bf16)fb;
      vl[e] = (__bf16)(fa - (float)vh[e]);
      vl[e + 4] = (__bf16)(fb - (float)vh[e + 4]);
    }
    *reinterpret_cast<bf16x8*>(&xh[r * WPITCH + k]) = vh;
    *reinterpret_cast<bf16x8*>(&xl[r * WPITCH + k]) = vl;
  }
  __syncthreads();

  const int rr = lane & 15;
  const int g8 = (lane >> 4) * 8;
  f32x4 acc[8] = {};
#pragma unroll
  for (int kk = 0; kk < 4; ++kk) {
    const int ko = kk * 32 + g8;
    const bf16x8 bh = *reinterpret_cast<const bf16x8*>(&xh[(wv * 16 + rr) * WPITCH + ko]);
    const bf16x8 bl = *reinterpret_cast<const bf16x8*>(&xl[(wv * 16 + rr) * WPITCH + ko]);
#pragma unroll
    for (int nc = 0; nc < 8; ++nc) {
      const bf16x8 af = *reinterpret_cast<const bf16x8*>(&Wlds[(nc * 16 + rr) * WPITCH + ko]);
      acc[nc] = __builtin_amdgcn_mfma_f32_16x16x32_bf16(af, bh, acc[nc], 0, 0, 0);
      acc[nc] = __builtin_amdgcn_mfma_f32_16x16x32_bf16(af, bl, acc[nc], 0, 0, 0);
    }
  }

  const int q4 = (lane >> 4) * 4;
  const int grow = r0 + wv * 16 + rr;
  const int bb = grow >> 10;
  const int lg = grow & 1023;
  float asum[4] = {0.f, 0.f, 0.f, 0.f};
  float adsum[4] = {0.f, 0.f, 0.f, 0.f};
#pragma unroll
  for (int nc = 0; nc < 8; ++nc) {
    const int n0 = nc * 16 + q4;
    const f32x4 bv = *reinterpret_cast<const f32x4*>(bias + n0);
    const f32x4 sv = *reinterpret_cast<const f32x4*>(att_src + n0);
    const f32x4 dv = *reinterpret_cast<const f32x4*>(att_dst + n0);
    const int h = nc >> 1;
#pragma unroll
    for (int reg = 0; reg < 4; ++reg) {
      const float v = acc[nc][reg] + bv[reg];
      const int n = n0 + reg;
      xpT[((size_t)bb * 128 + n) * 1024 + lg] = (_Float16)v;
      asum[h]  = fmaf(v, sv[reg], asum[h]);
      adsum[h] = fmaf(v, dv[reg], adsum[h]);
    }
  }
#pragma unroll
  for (int h = 0; h < 4; ++h) {
    asum[h]  += __shfl_xor(asum[h], 16);
    asum[h]  += __shfl_xor(asum[h], 32);
    adsum[h] += __shfl_xor(adsum[h], 16);
    adsum[h] += __shfl_xor(adsum[h], 32);
  }
  if ((lane >> 4) == 0) {
#pragma unroll
    for (int h = 0; h < 4; ++h) {
      const size_t o = ((size_t)bb * 4 + h) * 1024 + lg;
      E1h[o] = (_Float16)(16.0f * __expf(asum[h]));
      E2h[o] = (_Float16)__expf(0.2f * asum[h]);
      Rr[o]  = 16.0f * __expf(-0.8f * adsum[h]);
    }
  }
}

// ---------------------------------------------------------------------------
// Kernel 2 (flash attn, R17 shape, e1/e2 DIRECT FROM L2):
//   The e1/e2 LDS staging had ZERO reuse (each element read by exactly one
//   wave) - pure global->LDS->reg round-trip (common-mistake #7). Now the
//   main loop reads e1/e2 via two more 4-deep GLOBAL uint4 rings (same
//   proven pattern as xpT; deep vmcnt queue instead of shallow lgkm chain).
//   Mask stays in LDS (4x reuse across heads). LDS phase 1 = mask only.
// ---------------------------------------------------------------------------
__global__ __launch_bounds__(512, 2) void gat_attn_kernel(
    const unsigned* __restrict__ mask_g, const _Float16* __restrict__ xpT,
    const _Float16* __restrict__ E1h, const _Float16* __restrict__ E2h,
    const float* __restrict__ Rr, float* __restrict__ out)
{
  // phase 1: msk[64][176] (11.3 KB); phase 2 (after barrier):
  // comb[4][4][64][13] floats (53,248 B) OVERLAYS msk.
  __shared__ __align__(16) char smem[53248];
  unsigned char* msk = reinterpret_cast<unsigned char*>(smem);
  float* comb = reinterpret_cast<float*>(smem);

  const int wg  = blockIdx.x;     // 256 blocks
  const int xcd = wg & 7;
  const int idx = wg >> 3;
  const int b   = xcd * 2 + (idx & 1);
  const int i0  = (idx >> 1) * TI;

  const int t = threadIdx.x;
  const int wv = t >> 6;        // 0..7
  const int lane = t & 63;
  const int h  = wv >> 1;       // head
  const int jh = wv & 1;        // j-half

  // ---- staging: mask only ----
  {
    const int r = t >> 3, sg = t & 7;        // 64 rows x 8 segs of 16B
    const uint4 m = *reinterpret_cast<const uint4*>(
        mask_g + ((size_t)b * L_DIM + i0 + r) * 32 + sg * 4);
    *reinterpret_cast<uint4*>(&msk[r * 176 + sg * 16]) = m;
  }
  __syncthreads();

  const int ln15 = lane & 15;
  const int kh = lane >> 4;
  const int jb = kh * 8;
  const int base = jh * 512;
  const float* RrB = Rr + ((size_t)(b * H_DIM + h)) * L_DIM + i0 + ln15;
  f16x2 R2g[4];
#pragma unroll
  for (int g = 0; g < 4; ++g) {
    const _Float16 rh = (_Float16)RrB[g * 16];
    R2g[g][0] = rh; R2g[g][1] = rh;
  }
  const _Float16* xb0 = xpT + ((size_t)(b * 128 + h * 32 + ln15)) * 1024 + base;
  const _Float16* xb1 = xb0 + 16 * 1024;
  const _Float16* e1g = E1h + ((size_t)(b * H_DIM + h)) * 1024 + base;
  const _Float16* e2g = E2h + ((size_t)(b * H_DIM + h)) * 1024 + base;

  f32x4 acc0[4] = {}, acc1[4] = {}, accS[4] = {};
  f16x8 ones16;
#pragma unroll
  for (int e = 0; e < 8; ++e) ones16[e] = (_Float16)1.0f;

  // 4-deep global rings: xpT (2) + e1 + e2. Over-reads land in ws arrays.
  uint4 pf0[4], pf1[4], e1r[4], e2r[4];
#pragma unroll
  for (int s = 0; s < 4; ++s) {
    pf0[s] = *reinterpret_cast<const uint4*>(xb0 + s * 32 + jb);
    pf1[s] = *reinterpret_cast<const uint4*>(xb1 + s * 32 + jb);
    e1r[s] = *reinterpret_cast<const uint4*>(e1g + s * 32 + jb);
    e2r[s] = *reinterpret_cast<const uint4*>(e2g + s * 32 + jb);
  }
  uint4 mwc[4];   // per-group mask words, refreshed every 4 iters (128 j)

#pragma unroll 4
  for (int kr = 0; kr < 512; kr += 32) {
    const int tm = (kr >> 5) & 3;
    if (tm == 0) {
#pragma unroll
      for (int g = 0; g < 4; ++g)
        mwc[g] = *reinterpret_cast<const uint4*>(
            &msk[(g * 16 + ln15) * 176 + jh * 64 + (kr >> 7) * 16]);
    }
    unsigned mb[4];
#pragma unroll
    for (int g = 0; g < 4; ++g) {
      const unsigned w32 = (tm == 0) ? mwc[g].x : (tm == 1) ? mwc[g].y
                         : (tm == 2) ? mwc[g].z : mwc[g].w;
      mb[g] = (w32 >> (kh * 8)) & 0xffu;
    }

    // consume ring slots, refill 4 iters (128 j) ahead; over-reads safe (ws)
    const int sl = (kr >> 5) & 3;
    const uint4 bb0 = pf0[sl];
    const uint4 bb1 = pf1[sl];
    const uint4 u1c = e1r[sl];
    const uint4 u2c = e2r[sl];
    pf0[sl] = *reinterpret_cast<const uint4*>(xb0 + kr + 128 + jb);
    pf1[sl] = *reinterpret_cast<const uint4*>(xb1 + kr + 128 + jb);
    e1r[sl] = *reinterpret_cast<const uint4*>(e1g + kr + 128 + jb);
    e2r[sl] = *reinterpret_cast<const uint4*>(e2g + kr + 128 + jb);

    const unsigned uu1[4] = {u1c.x, u1c.y, u1c.z, u1c.w};
    const unsigned uu2[4] = {u2c.x, u2c.y, u2c.z, u2c.w};
    unsigned rg[4][4];
#pragma unroll
    for (int q = 0; q < 4; ++q) {
      f16x2 a, ee;
      __builtin_memcpy(&a,  &uu1[q], 4);
      __builtin_memcpy(&ee, &uu2[q], 4);
#pragma unroll
      for (int g = 0; g < 4; ++g) {
        const f16x2 pr = ee * R2g[g];                         // v_pk_mul_f16
        const f16x2 mx = __builtin_elementwise_max(a, pr);    // v_pk_max_f16
        unsigned mu;
        __builtin_memcpy(&mu, &mx, 4);
        const unsigned mlo = (mb[g] & (1u << (2 * q)))     ? 0xFFFFu : 0u;
        const unsigned mhi = (mb[g] & (1u << (2 * q + 1))) ? 0xFFFF0000u : 0u;
        rg[g][q] = mu & (mlo | mhi);
      }
    }
    f16x8 b0h, b1h;
    __builtin_memcpy(&b0h, &bb0, 16);
    __builtin_memcpy(&b1h, &bb1, 16);
#pragma unroll
    for (int g = 0; g < 4; ++g) {
      const uint4 afu = {rg[g][0], rg[g][1], rg[g][2], rg[g][3]};
      f16x8 af;
      __builtin_memcpy(&af, &afu, 16);
      acc0[g] = __builtin_amdgcn_mfma_f32_16x16x32_f16(af, b0h, acc0[g], 0, 0, 0);
      acc1[g] = __builtin_amdgcn_mfma_f32_16x16x32_f16(af, b1h, acc1[g], 0, 0, 0);
      accS[g] = __builtin_amdgcn_mfma_f32_16x16x32_f16(af, ones16, accS[g], 0, 0, 0);
    }
  }

  // ---- combine: jh=1 dumps partials; jh=0 adds, normalizes, stores ----
  __syncthreads();                       // mask reads complete before overlay
  if (jh == 1) {
#pragma unroll
    for (int g = 0; g < 4; ++g) {
      float* cp = &comb[((h * 4 + g) * 64 + lane) * 13];
#pragma unroll
      for (int e = 0; e < 4; ++e) {
        cp[e]     = acc0[g][e];
        cp[4 + e] = acc1[g][e];
        cp[8 + e] = accS[g][e];
      }
    }
  }
  __syncthreads();
  if (jh == 0) {
#pragma unroll
    for (int g = 0; g < 4; ++g) {
      const float* cp = &comb[((h * 4 + g) * 64 + lane) * 13];
#pragma unroll
      for (int reg = 0; reg < 4; ++reg) {
        const float s = accS[g][reg] + cp[8 + reg];
        const float rs = 1.0f / s;
        float* op = out + ((size_t)(b * L_DIM + i0 + g * 16 + kh * 4 + reg)) * HC + h * 32;
        op[ln15]      = (acc0[g][reg] + cp[reg])     * rs;
        op[16 + ln15] = (acc1[g][reg] + cp[4 + reg]) * rs;
      }
    }
  }
}

extern "C" void kernel_launch(void* const* d_in, const int* in_sizes, int n_in,
                              void* d_out, int out_size, void* d_ws, size_t ws_size,
                              hipStream_t stream) {
  (void)in_sizes; (void)n_in; (void)out_size; (void)ws_size;
  const float* x        = (const float*)d_in[0];
  const int*   adj      = (const int*)d_in[1];
  const float* W        = (const float*)d_in[2];
  const float* bias     = (const float*)d_in[3];
  const float* att_src  = (const float*)d_in[4];
  const float* att_dst  = (const float*)d_in[5];
  float* out = (float*)d_out;

  char* ws = (char*)d_ws;
  _Float16* xpT    = (_Float16*)ws;                                    // 4 MiB
  _Float16* E1h    = (_Float16*)(ws + (size_t)4 * 1024 * 1024);        // 128 KiB
  _Float16* E2h    = (_Float16*)(ws + (size_t)4 * 1024 * 1024 + 131072);
  float*    Rr     = (float*)(ws + (size_t)4 * 1024 * 1024 + 262144);  // 256 KiB
  unsigned* mask_g = (unsigned*)(ws + (size_t)4 * 1024 * 1024 + 524288); // 2 MiB

  hipLaunchKernelGGL(prep_kernel, dim3(PROJ_BLOCKS + B_DIM * L_DIM / 8), dim3(256), 0, stream,
                     x, W, bias, att_src, att_dst, adj, xpT, E1h, E2h, Rr, mask_g);
  hipLaunchKernelGGL(gat_attn_kernel, dim3(B_DIM * L_DIM / TI), dim3(512), 0, stream,
                     mask_g, xpT, E1h, E2h, Rr, out);
}